// Round 5
// baseline (177.026 us; speedup 1.0000x reference)
//
#include <hip/hip_runtime.h>

// OverlapPatchEmbed: x (64,3,224,224) fp32 -> out (64,729,3,256) fp32.
// patch=16, stride=8, n=27 patches/dim.
//
// R4 = R3 with the nontemporal-store type fixed (builtin requires a native
// clang vector type, not HIP_vector_type).
//
// Block = (b, py) covering ALL 3 channels. Stage the 3x16x224 band
// (43.7 KB LDS, row stride 228 floats for bank spread) with coalesced
// loads, then emit the 27 patches x 3 ch x 1 KB = 81 KB output region
// PERFECTLY SEQUENTIALLY. Output is write-once -> nontemporal stores.
// Occupancy: 512 thr, 43.7 KB LDS -> 3 blocks/CU = 24 waves/CU.

typedef float nfloat4 __attribute__((ext_vector_type(4)));  // native vec for builtins

constexpr int NB  = 64;
constexpr int NC  = 3;
constexpr int HWD = 224;
constexpr int PS  = 16;    // patch size
constexpr int ST  = 8;     // stride
constexpr int NP  = 27;    // patches per dim
constexpr int ROW4 = HWD / 4;          // 56 float4 per image row
constexpr int LDSW = 228;              // LDS row stride in floats (+4 pad)
constexpr int TPB  = 512;
constexpr int NLOAD4  = NC * PS * ROW4;      // 2688 float4 staged per block
constexpr int NSTORE4 = NP * NC * 64;        // 5184 float4 written per block

__global__ __launch_bounds__(TPB) void overlap_patch_seq(
    const nfloat4* __restrict__ x, nfloat4* __restrict__ out)
{
    const int py = blockIdx.x % NP;
    const int b  = blockIdx.x / NP;

    __shared__ float lds[NC * PS * LDSW];   // 43776 B

    const int t = threadIdx.x;

    // Stage 1: load 3 channel-bands of 16 rows x 56 float4, coalesced.
    #pragma unroll
    for (int k = 0; k < 6; ++k) {
        const int j = t + k * TPB;
        if (j < NLOAD4) {
            const int c    = j / (PS * ROW4);        // 0..2
            const int rem  = j - c * (PS * ROW4);
            const int r    = rem / ROW4;             // 0..15
            const int col4 = rem - r * ROW4;         // 0..55
            const nfloat4 v = x[((b * NC + c) * HWD + py * ST + r) * ROW4 + col4];
            *(nfloat4*)&lds[(c * PS + r) * LDSW + col4 * 4] = v;
        }
    }
    __syncthreads();

    // Stage 2: write 81 KB sequentially. Output float4 index j maps to
    // px = j/192, c = (j%192)/64, q4 = j%64; r = q4>>2, s = (q4&3)*4.
    const long obase = (long)(b * NP * NP + py * NP) * (NC * 64);  // float4
    #pragma unroll
    for (int k = 0; k < 11; ++k) {
        const int j = t + k * TPB;
        if (j < NSTORE4) {
            const int px  = j / (NC * 64);
            const int rem = j - px * (NC * 64);
            const int c   = rem >> 6;
            const int q4  = rem & 63;
            const int r   = q4 >> 2;
            const int s   = (q4 & 3) << 2;
            const nfloat4 v = *(const nfloat4*)&lds[(c * PS + r) * LDSW + px * ST + s];
            __builtin_nontemporal_store(v, &out[obase + j]);
        }
    }
}

extern "C" void kernel_launch(void* const* d_in, const int* in_sizes, int n_in,
                              void* d_out, int out_size, void* d_ws, size_t ws_size,
                              hipStream_t stream) {
    const nfloat4* x = (const nfloat4*)d_in[0];
    nfloat4* out = (nfloat4*)d_out;
    const int grid = NB * NP;   // 1728 blocks
    overlap_patch_seq<<<grid, TPB, 0, stream>>>(x, out);
}

// Round 6
// 171.873 us; speedup vs baseline: 1.0300x; 1.0300x over previous
//
#include <hip/hip_runtime.h>

// OverlapPatchEmbed: x (64,3,224,224) fp32 -> out (64,729,3,256) fp32.
// patch=16, stride=8, n=27 patches/dim.
//
// R5 = R4 without nontemporal stores (nt was neutral-to-negative; plain
// stores match the 6.8 TB/s write path the harness fill kernels achieve).
//
// Block = (b, py) covering ALL 3 channels. Stage the 3x16x224 band
// (43.7 KB LDS, row stride 228 floats) with coalesced loads, then emit
// the 27 patches x 3 ch x 1 KB = 81 KB output region PERFECTLY
// SEQUENTIALLY (out float4 index == loop index).
// Occupancy: 512 thr, 43.7 KB LDS -> 3 blocks/CU = 24 waves/CU.
// Stage-2 ds_read_b128 bank distribution is uniform (8 lanes per bank
// quad = the b128 floor), so LDS is not a bottleneck.

typedef float nfloat4 __attribute__((ext_vector_type(4)));

constexpr int NB  = 64;
constexpr int NC  = 3;
constexpr int HWD = 224;
constexpr int PS  = 16;    // patch size
constexpr int ST  = 8;     // stride
constexpr int NP  = 27;    // patches per dim
constexpr int ROW4 = HWD / 4;          // 56 float4 per image row
constexpr int LDSW = 228;              // LDS row stride in floats (+4 pad)
constexpr int TPB  = 512;
constexpr int NLOAD4  = NC * PS * ROW4;      // 2688 float4 staged per block
constexpr int NSTORE4 = NP * NC * 64;        // 5184 float4 written per block

__global__ __launch_bounds__(TPB) void overlap_patch_seq(
    const nfloat4* __restrict__ x, nfloat4* __restrict__ out)
{
    const int py = blockIdx.x % NP;
    const int b  = blockIdx.x / NP;

    __shared__ float lds[NC * PS * LDSW];   // 43776 B

    const int t = threadIdx.x;

    // Stage 1: load 3 channel-bands of 16 rows x 56 float4, coalesced.
    #pragma unroll
    for (int k = 0; k < 6; ++k) {
        const int j = t + k * TPB;
        if (j < NLOAD4) {
            const int c    = j / (PS * ROW4);        // 0..2
            const int rem  = j - c * (PS * ROW4);
            const int r    = rem / ROW4;             // 0..15
            const int col4 = rem - r * ROW4;         // 0..55
            const nfloat4 v = x[((b * NC + c) * HWD + py * ST + r) * ROW4 + col4];
            *(nfloat4*)&lds[(c * PS + r) * LDSW + col4 * 4] = v;
        }
    }
    __syncthreads();

    // Stage 2: write 81 KB sequentially. Output float4 index j maps to
    // px = j/192, c = (j%192)/64, q4 = j%64; r = q4>>2, s = (q4&3)*4.
    const long obase = (long)(b * NP * NP + py * NP) * (NC * 64);  // float4
    #pragma unroll
    for (int k = 0; k < 11; ++k) {
        const int j = t + k * TPB;
        if (j < NSTORE4) {
            const int px  = j / (NC * 64);
            const int rem = j - px * (NC * 64);
            const int c   = rem >> 6;
            const int q4  = rem & 63;
            const int r   = q4 >> 2;
            const int s   = (q4 & 3) << 2;
            const nfloat4 v = *(const nfloat4*)&lds[(c * PS + r) * LDSW + px * ST + s];
            out[obase + j] = v;
        }
    }
}

extern "C" void kernel_launch(void* const* d_in, const int* in_sizes, int n_in,
                              void* d_out, int out_size, void* d_ws, size_t ws_size,
                              hipStream_t stream) {
    const nfloat4* x = (const nfloat4*)d_in[0];
    nfloat4* out = (nfloat4*)d_out;
    const int grid = NB * NP;   // 1728 blocks
    overlap_patch_seq<<<grid, TPB, 0, stream>>>(x, out);
}